// Round 1
// 442.895 us; speedup vs baseline: 1.1021x; 1.1021x over previous
//
#include <hip/hip_runtime.h>
#include <cstdint>

typedef __attribute__((ext_vector_type(8))) _Float16 f16x8;
typedef __attribute__((ext_vector_type(4))) float f32x4;

#define SEQL 256

// ws byte offsets (prep output; identical layout to prior rounds)
#define WS_B0H   0        // [3 kstep][16 ntile][64 lane][8] f16 = 49152 B
#define WS_B0L   49152    // lo pre-scaled x2048
#define WS_B1H   98304    // [4][16][64][8] f16 hi = 65536 B, then lo contiguous
#define WS_BIAS0 229376   // 256 f32, index = cell*4+gate, pre-scaled
#define WS_BIAS1 230400

// LDS: single f16 A buffer. Row = 656 B = 164 words (residue 4 mod 32:
// groups of 8 lanes tile all 32 banks -> b128 conflict-free).
// byte offs in row: x0@0(64B) x1@64 h1_0@128(128B) h1_1@256 h2_0@384 h2_1@512 pad@640
#define ASTR 656
#define L_A  0            // 16 x 656 = 10496
#define L_HD 10496        // head exchange: 16 rows x 272 B
#define HDSTR 272
#define LDS_TOTAL 14848

#define NEG_L   -1.4426950408889634f   // -log2(e)
#define NEG_2L  -2.8853900817779268f   // -2*log2(e)
#define LO_SCALE 2048.0f
#define LO_INV   4.8828125e-4f         // 1/2048

__device__ __forceinline__ float ex2(float x) { return __builtin_amdgcn_exp2f(x); }
__device__ __forceinline__ float rcp_(float x) { return __builtin_amdgcn_rcpf(x); }
__device__ __forceinline__ f32x4 mfma16(f16x8 a, f16x8 b, f32x4 c) {
  return __builtin_amdgcn_mfma_f32_16x16x32_f16(a, b, c, 0, 0, 0);
}
__device__ __forceinline__ f16x8 zero8() {
  f16x8 z;
#pragma unroll
  for (int i = 0; i < 8; ++i) z[i] = (_Float16)0.f;
  return z;
}

// Pack weights into MFMA fragment order (A/B f16 fragment layouts are
// identical on gfx950: 16-dim on lane&15, K on (lane>>4)*8+j), f16 hi +
// f16 lo(x2048) split, pre-scaled by -log2e (i,f,o) / -2log2e (g).
// UNCHANGED from prior rounds — the same bytes now feed the A-operand.
__global__ __launch_bounds__(256) void prep(
    const float* __restrict__ Wih0, const float* __restrict__ Whh0,
    const float* __restrict__ bih0, const float* __restrict__ bhh0,
    const float* __restrict__ Wih1, const float* __restrict__ Whh1,
    const float* __restrict__ bih1, const float* __restrict__ bhh1,
    unsigned char* __restrict__ ws) {
  int e = blockIdx.x * 256 + threadIdx.x;
  if (e < 24576) {  // B0: K=96 = [x(32)|h1(64)]
    int j = e & 7, lane = (e >> 3) & 63, nt = (e >> 9) & 15, ks = e >> 13;
    int kdim = ks * 32 + (lane >> 4) * 8 + j;
    int col = nt * 16 + (lane & 15);   // now the GATE-ROW index of the A-operand
    int ko = col >> 2, g = col & 3;
    float w = (kdim < 32) ? Wih0[(g * 64 + ko) * 32 + kdim]
                          : Whh0[(g * 64 + ko) * 64 + (kdim - 32)];
    w *= (g == 2) ? NEG_2L : NEG_L;
    _Float16 hi = (_Float16)w;
    _Float16 lo = (_Float16)((w - (float)hi) * LO_SCALE);
    ((_Float16*)(ws + WS_B0H))[e] = hi;
    ((_Float16*)(ws + WS_B0L))[e] = lo;
  } else if (e < 57344) {  // B1: K=128 = [h1(64)|h2(64)]
    int r = e - 24576;
    int j = r & 7, lane = (r >> 3) & 63, nt = (r >> 9) & 15, ks = r >> 13;
    int kdim = ks * 32 + (lane >> 4) * 8 + j;
    int col = nt * 16 + (lane & 15);
    int ko = col >> 2, g = col & 3;
    float w = (kdim < 64) ? Wih1[(g * 64 + ko) * 64 + kdim]
                          : Whh1[(g * 64 + ko) * 64 + (kdim - 64)];
    w *= (g == 2) ? NEG_2L : NEG_L;
    _Float16 hi = (_Float16)w;
    _Float16 lo = (_Float16)((w - (float)hi) * LO_SCALE);
    ((_Float16*)(ws + WS_B1H))[r] = hi;
    ((_Float16*)(ws + WS_B1H + 65536))[r] = lo;
  } else if (e < 57856) {  // biases (pre-scaled, fp32)
    int r = e - 57344;
    int col = r & 255, ko = col >> 2, g = col & 3;
    float v = (r < 256) ? bih0[g * 64 + ko] + bhh0[g * 64 + ko]
                        : bih1[g * 64 + ko] + bhh1[g * 64 + ko];
    v *= (g == 2) ? NEG_2L : NEG_L;
    ((float*)(ws + (r < 256 ? WS_BIAS0 : WS_BIAS1)))[col] = v;
  }
}

// v6: operand-swapped MFMA (W as A, activations as B) so each lane's 4 acc
// regs ARE i,f,g,o of one (batch,cell) — no quad_transpose. Layers skewed:
// each barrier interval computes L1(t) and L2(t-1) as independent chains.
__global__ __launch_bounds__(1024, 4) void lstm_mfma6(
    const float* __restrict__ x, const unsigned char* __restrict__ ws,
    const float* __restrict__ W1, const float* __restrict__ b1,
    const float* __restrict__ W2, const float* __restrict__ b2,
    float* __restrict__ out) {
  __shared__ __align__(16) unsigned char lds[LDS_TOTAL];
  const int tid = threadIdx.x;
  const int lane = tid & 63, wave = tid >> 6;  // 16 waves, 1 gate-row-tile each
  const int q = lane >> 4, bcol = lane & 15;   // bcol = batch column (D col)

  // ---- Weight fragments -> registers (loop-invariant, A-operand) ----
  f16x8 b0h[3], b0l[3], b1h[4], b1l[4];
#pragma unroll
  for (int ks = 0; ks < 3; ++ks) {
    int rec = (ks * 16 + wave) * 64 + lane;
    b0h[ks] = ((const f16x8*)(ws + WS_B0H))[rec];
    b0l[ks] = ((const f16x8*)(ws + WS_B0L))[rec];
  }
#pragma unroll
  for (int ks = 0; ks < 4; ++ks) {
    int rec = (ks * 16 + wave) * 64 + lane;
    b1h[ks] = ((const f16x8*)(ws + WS_B1H))[rec];
    b1l[ks] = ((const f16x8*)(ws + WS_B1H + 65536))[rec];
  }
  // Per-lane bias: D rows wave*16+q*4+{0..3} = gates i,f,g,o of cell wave*4+q
  const f32x4 bias0v = ((const f32x4*)(ws + WS_BIAS0))[wave * 4 + q];
  const f32x4 bias1v = ((const f32x4*)(ws + WS_BIAS1))[wave * 4 + q];
  f32x4 z4;
  z4[0] = z4[1] = z4[2] = z4[3] = 0.f;

  // Zero A buffer (10496 B = 2624 words) — also provides h1(-1)=h2(-1)=0
  for (int i = tid; i < 2624; i += 1024) ((unsigned*)(lds + L_A))[i] = 0u;

  // x staging role (threads 0..511): bx = tid>>5 (0..15), d = tid&31
  const bool do_x = tid < 512;
  const int bx = tid >> 5, d = tid & 31;
  const float* xcol = x + (size_t)(blockIdx.x * 16 + (do_x ? bx : 0)) * (SEQL * 32) + d;
  if (do_x) {
    *(_Float16*)(lds + L_A + bx * ASTR + d * 2) = (_Float16)xcol[0];  // x(0)
  }

  const int ard = bcol * ASTR + q * 16;               // B-frag read base
  const int hwr = bcol * ASTR + (wave * 4 + q) * 2;   // h write base (in-slot)

  float c1 = 0.f, c2 = 0.f, h2f = 0.f;
  f16x8 ah1[2], ah2[2], ax;
  ah1[0] = ah1[1] = ah2[0] = ah2[1] = zero8();
  __syncthreads();
  ax = *(const f16x8*)(lds + L_A + ard + 0);  // x(0), slot par=0

  // 4 acc regs = i,f,g,o directly. sigma = rcp(1+2^v); tanh = 2*rcp(1+2^v)-1
  // (weights/biases pre-scaled by -log2e / -2log2e). Saturation is graceful:
  // 2^v -> inf -> rcp -> 0.
  auto cell = [&](const f32x4& aH, const f32x4& aL, float& c) -> float {
    float p0 = fmaf(aL[0], LO_INV, aH[0]);
    float p1 = fmaf(aL[1], LO_INV, aH[1]);
    float p2 = fmaf(aL[2], LO_INV, aH[2]);
    float p3 = fmaf(aL[3], LO_INV, aH[3]);
    float gi = rcp_(1.f + ex2(p0));
    float gf = rcp_(1.f + ex2(p1));
    float gg = fmaf(2.f, rcp_(1.f + ex2(p2)), -1.f);
    float go = rcp_(1.f + ex2(p3));
    c = fmaf(gf, c, gi * gg);
    float tc = fmaf(2.f, rcp_(1.f + ex2(c * NEG_2L)), -1.f);
    return go * tc;
  };

  // One barrier per t. Computes L1(t) (G0) and L2(t-1) (G1) concurrently.
  // All activation reads happen right after the barrier (pre-covered latency).
  auto iter = [&](int t, int par, bool doL2) {
    const int h1s = 128 + par * 128;   // h1(t) slot
    const int h2s = 384 + par * 128;   // h2(t-1) slot
    const int xwr = (par ^ 1) * 64;    // x(t+1) slot
    float xnext = 0.f;
    if (do_x && t < SEQL - 1) xnext = xcol[(t + 1) * 32];

    // G0 = bias0 + W0 @ [x(t)|h1(t-1)]  ;  G1 = bias1 + W1 @ [h1(t-1)|h2(t-2)]
    f32x4 aH0 = mfma16(b0h[0], ax, bias0v);
    f32x4 aL0 = mfma16(b0l[0], ax, z4);
    f32x4 aH1 = mfma16(b1h[0], ah1[0], bias1v);
    f32x4 aL1 = mfma16(b1l[0], ah1[0], z4);
    aH1 = mfma16(b1h[1], ah1[1], aH1);
    aL1 = mfma16(b1l[1], ah1[1], aL1);
#pragma unroll
    for (int ks = 0; ks < 2; ++ks) {
      aH0 = mfma16(b0h[ks + 1], ah1[ks], aH0);
      aL0 = mfma16(b0l[ks + 1], ah1[ks], aL0);
      aH1 = mfma16(b1h[ks + 2], ah2[ks], aH1);
      aL1 = mfma16(b1l[ks + 2], ah2[ks], aL1);
    }
    // Cell 1 -> h1(t)
    float h1 = cell(aH0, aL0, c1);
    *(_Float16*)(lds + L_A + hwr + h1s) = (_Float16)h1;
    // Cell 2 -> h2(t-1)
    if (doL2) {
      float h2 = cell(aH1, aL1, c2);
      *(_Float16*)(lds + L_A + hwr + h2s) = (_Float16)h2;
    }
    if (do_x && t < SEQL - 1) {
      *(_Float16*)(lds + L_A + bx * ASTR + xwr + d * 2) = (_Float16)xnext;
    }
    __syncthreads();  // the ONLY barrier per step
    // Reads for t+1 (WAR vs next writes separated by the next barrier,
    // same discipline as prior rounds)
    ah1[0] = *(const f16x8*)(lds + L_A + ard + h1s);
    ah1[1] = *(const f16x8*)(lds + L_A + ard + h1s + 64);
    ah2[0] = *(const f16x8*)(lds + L_A + ard + h2s);
    ah2[1] = *(const f16x8*)(lds + L_A + ard + h2s + 64);
    ax     = *(const f16x8*)(lds + L_A + ard + xwr);
  };

  iter(0, 0, false);  // L1(0) only; h2 slot stays zero => h2(-1)=0
#pragma unroll 1
  for (int tp = 0; tp < 127; ++tp) {
    iter(2 * tp + 1, 1, true);
    iter(2 * tp + 2, 0, true);
  }
  iter(255, 1, true);  // L1(255) + L2(254); bottom reads h1(255), h2(254)

  // ---- Epilogue: L2(255) -> h2f ----
  {
    f32x4 aH = mfma16(b1h[0], ah1[0], bias1v);
    f32x4 aL = mfma16(b1l[0], ah1[0], z4);
    aH = mfma16(b1h[1], ah1[1], aH);
    aL = mfma16(b1l[1], ah1[1], aL);
#pragma unroll
    for (int ks = 0; ks < 2; ++ks) {
      aH = mfma16(b1h[ks + 2], ah2[ks], aH);
      aL = mfma16(b1l[ks + 2], ah2[ks], aL);
    }
    h2f = cell(aH, aL, c2);
  }

  // ---- Head: f = relu(h2 @ W1.T + b1); out = f @ W2.T + b2 (fp32 h2) ----
  __syncthreads();
  *(float*)(lds + L_HD + bcol * HDSTR + (wave * 4 + q) * 4) = h2f;
  __syncthreads();
  if (tid < 256) {
    const int s = tid & 15, bo = tid >> 4;
    const float* h2row = (const float*)(lds + L_HD + bo * HDSTR);
    float partial = 0.f;
#pragma unroll
    for (int kk4 = 0; kk4 < 4; ++kk4) {
      int kk = s * 4 + kk4;
      float f = b1[kk];
#pragma unroll
      for (int j = 0; j < 64; j += 4) {
        f32x4 w = *(const f32x4*)(W1 + kk * 64 + j);
        f = fmaf(w[0], h2row[j], f);
        f = fmaf(w[1], h2row[j + 1], f);
        f = fmaf(w[2], h2row[j + 2], f);
        f = fmaf(w[3], h2row[j + 3], f);
      }
      f = fmaxf(f, 0.f);
      partial = fmaf(f, W2[kk], partial);
    }
    partial += __shfl_xor(partial, 8, 64);
    partial += __shfl_xor(partial, 4, 64);
    partial += __shfl_xor(partial, 2, 64);
    partial += __shfl_xor(partial, 1, 64);
    if (s == 0) out[blockIdx.x * 16 + bo] = partial + b2[0];
  }
}

extern "C" void kernel_launch(void* const* d_in, const int* in_sizes, int n_in,
                              void* d_out, int out_size, void* d_ws, size_t ws_size,
                              hipStream_t stream) {
  const float* x    = (const float*)d_in[0];
  const float* Wih0 = (const float*)d_in[1];
  const float* Whh0 = (const float*)d_in[2];
  const float* bih0 = (const float*)d_in[3];
  const float* bhh0 = (const float*)d_in[4];
  const float* Wih1 = (const float*)d_in[5];
  const float* Whh1 = (const float*)d_in[6];
  const float* bih1 = (const float*)d_in[7];
  const float* bhh1 = (const float*)d_in[8];
  const float* W1   = (const float*)d_in[9];
  const float* b1   = (const float*)d_in[10];
  const float* W2   = (const float*)d_in[11];
  const float* b2   = (const float*)d_in[12];
  unsigned char* ws = (unsigned char*)d_ws;
  float* out = (float*)d_out;

  prep<<<(57856 + 255) / 256, 256, 0, stream>>>(Wih0, Whh0, bih0, bhh0,
                                                Wih1, Whh1, bih1, bhh1, ws);
  lstm_mfma6<<<256, 1024, 0, stream>>>(x, ws, W1, b1, W2, b2, out);
}